// Round 11
// baseline (167.963 us; speedup 1.0000x reference)
//
#include <hip/hip_runtime.h>
#include <hip/hip_bf16.h>

typedef __attribute__((ext_vector_type(4))) float f32x4;
typedef __attribute__((ext_vector_type(16))) float f32x16;
typedef __attribute__((ext_vector_type(8))) short bf8;
typedef __attribute__((ext_vector_type(2))) int i32x2;

#define B_ 2
#define ST 2048
#define SC 1024
#define SK 3072
#define NH 16
#define DH 128
#define KVB 32
#define NTG 48           // tiles per KV-group (2 groups x 48 = 96)
#define TGT 64           // global tile index where cond bias starts
#define SCALE 0.088388347648318447f

__device__ __forceinline__ unsigned short f2bf(float f) {
    union { __hip_bfloat16 b; unsigned short u; } c;
    c.b = __float2bfloat16(f);
    return c.u;
}

__device__ __forceinline__ i32x2 tr_read(unsigned a) {
    i32x2 d;
    asm volatile("ds_read_b64_tr_b16 %0, %1" : "=v"(d) : "v"(a));
    return d;
}

__device__ __forceinline__ unsigned cvtpk(float lo, float hi) {
    unsigned r;
    asm("v_cvt_pk_bf16_f32 %0, %1, %2" : "=v"(r) : "v"(lo), "v"(hi));
    return r;
}

// v_permlane32_swap_b32: SAFE only with two independently-computed values
// (P-pack, proven R7). BROKEN as copy-then-swap self-reduce (R6/R8).
__device__ __forceinline__ void swap32(unsigned &a, unsigned &b) {
    asm volatile("v_permlane32_swap_b32 %0, %1" : "+v"(a), "+v"(b));
}
__device__ __forceinline__ float xmax32(float x) {
    return fmaxf(x, __shfl_xor(x, 32));
}
__device__ __forceinline__ float xsum32(float x) {
    return x + __shfl_xor(x, 32);
}

__device__ __forceinline__ bf8 pack_bf8(f32x4 a, f32x4 b) {
    bf8 v;
    v[0]=(short)f2bf(a[0]); v[1]=(short)f2bf(a[1]);
    v[2]=(short)f2bf(a[2]); v[3]=(short)f2bf(a[3]);
    v[4]=(short)f2bf(b[0]); v[5]=(short)f2bf(b[1]);
    v[6]=(short)f2bf(b[2]); v[7]=(short)f2bf(b[3]);
    return v;
}

__device__ __forceinline__ bf8 mk_bf8(i32x2 a, i32x2 b) {
    union { i32x2 h[2]; bf8 v; } u;
    u.h[0] = a; u.h[1] = b;
    return u.v;
}
__device__ __forceinline__ bf8 mk_bf8w(unsigned w0, unsigned w1, unsigned w2, unsigned w3) {
    union { unsigned w[4]; bf8 v; } u;
    u.w[0] = w0; u.w[1] = w1; u.w[2] = w2; u.w[3] = w3;
    return u.v;
}

// NOTE: HIP __launch_bounds__ arg2 = min BLOCKS per CU (CUDA semantics —
// R4 evidence: (512,4) forced VGPR=64). (512,2) -> 16 waves/CU -> VGPR cap 128.
__global__ __launch_bounds__(512, 2)
void attn_fwd(const float* __restrict__ Q,
              const float* __restrict__ TK,
              const float* __restrict__ TV,
              const float* __restrict__ CK,
              const float* __restrict__ CV,
              const float* __restrict__ BP,
              float* __restrict__ OUT)
{
    // Split-KV flash: 8 waves. Group g = waves [4g,4g+4) process the SAME
    // 128 q-rows over KV tiles [g*48, g*48+48). Exact merge via LDS at end.
    // Per-group core identical to R9 (swapped QK^T/PV, q = lane&31).
    // SM layout: [0,32K) K buffers [g][dbuf] x 8KB; [32K,64K) V buffers;
    //            epilogue reuse: [0,64K) O-transfer (4 waves x 16KB);
    //            [64K, 64K+1K) m/l publish.
    __shared__ __align__(16) char SM[66560];

    const int tid  = threadIdx.x;
    const int g    = tid >> 8;         // KV-half group
    const int t256 = tid & 255;
    const int w4   = t256 >> 6;        // wave within group
    const int l    = tid & 63;
    const int r31  = l & 31;
    const int hi   = l >> 5;

    // XCD-aware mapping: 512 blocks = 8 XCD x 4 bh x 16 q-tiles
    const int bid = blockIdx.x;
    const int xcd = bid & 7;
    const int sub = bid >> 3;
    const int bh  = xcd * 4 + (sub >> 4);
    const int qt  = sub & 15;
    const int bb  = bh >> 4;
    const int hh  = bh & 15;

    const float bias_c = BP[0];

    // ---- Q fragments (B-operand): lane holds Q[q=r31][d=16dk+8hi+j], scaled ----
    const int qrow = qt * 128 + w4 * 32 + r31;
    const float* qp = Q + (((size_t)bb * ST + qrow) * NH + hh) * DH;
    bf8 qf[8];
#pragma unroll
    for (int dk = 0; dk < 8; ++dk) {
        const f32x4 x0 = *(const f32x4*)(qp + dk * 16 + hi * 8);
        const f32x4 x1 = *(const f32x4*)(qp + dk * 16 + hi * 8 + 4);
        bf8 v;
        v[0]=(short)f2bf(x0[0]*SCALE); v[1]=(short)f2bf(x0[1]*SCALE);
        v[2]=(short)f2bf(x0[2]*SCALE); v[3]=(short)f2bf(x0[3]*SCALE);
        v[4]=(short)f2bf(x1[0]*SCALE); v[5]=(short)f2bf(x1[1]*SCALE);
        v[6]=(short)f2bf(x1[2]*SCALE); v[7]=(short)f2bf(x1[3]*SCALE);
        qf[dk] = v;
    }

    f32x16 oa[4];
#pragma unroll
    for (int dt = 0; dt < 4; ++dt)
#pragma unroll
        for (int e = 0; e < 16; ++e) oa[dt][e] = 0.f;
    float m_run = -1e30f, l_run = 0.f;

    // staging registers (issue-early / write-late)
    f32x4 skr[2][2], svr[2][2];

    auto stage_load = [&](int t) {
        const int kv0 = (g * NTG + t) * KVB;
        const float *kb, *vb;
        if (kv0 < ST) {
            const size_t off = (((size_t)bb * ST + kv0) * NH + hh) * DH;
            kb = TK + off; vb = TV + off;
        } else {
            const size_t off = (((size_t)bb * SC + (kv0 - ST)) * NH + hh) * DH;
            kb = CK + off; vb = CV + off;
        }
#pragma unroll
        for (int i = 0; i < 2; ++i) {
            const int c = t256 + (i << 8);         // 0..511 16B chunks
            const int krow = c >> 4;
            const int kcol = ((c & 15) ^ (krow & 7)) << 3;
            const float* kp = kb + (size_t)krow * (NH * DH) + kcol;
            skr[i][0] = *(const f32x4*)kp;
            skr[i][1] = *(const f32x4*)(kp + 4);
            const int vkv = (((c >> 8) & 1) << 4) | (((c >> 4) & 1) << 3)
                          | (((c >> 7) & 1) << 2) | ((c >> 1) & 3);
            const int vd  = (((c >> 5) & 3) << 5) | (((c >> 3) & 1) << 4)
                          | ((c & 1) << 3);
            const float* vp = vb + (size_t)vkv * (NH * DH) + vd;
            svr[i][0] = *(const f32x4*)vp;
            svr[i][1] = *(const f32x4*)(vp + 4);
        }
    };

    auto stage_write = [&](int buf) {
        char* kd = SM + (((g << 1) | buf) << 13);
        char* vd = SM + 32768 + (((g << 1) | buf) << 13);
#pragma unroll
        for (int i = 0; i < 2; ++i) {
            const int c = t256 + (i << 8);
            *(bf8*)(kd + c * 16) = pack_bf8(skr[i][0], skr[i][1]);
            *(bf8*)(vd + c * 16) = pack_bf8(svr[i][0], svr[i][1]);
        }
    };

    stage_load(0);
    stage_write(0);

    const unsigned smBase = (unsigned)(size_t)SM;
    const unsigned vLaneOff = (unsigned)((l >> 4) * 128 + (l & 15) * 8);

    for (int t = 0; t < NTG; ++t) {
        __syncthreads();
        if (t + 1 < NTG) stage_load(t + 1);
        const int buf = t & 1;
        const float bias = (g * NTG + t >= TGT) ? bias_c : 0.f;
        const char* kB = SM + (((g << 1) | buf) << 13);

        // ---- QK^T swapped: two interleaved accumulators ----
        f32x16 s0, s1;
#pragma unroll
        for (int e = 0; e < 16; ++e) { s0[e] = 0.f; s1[e] = 0.f; }
        __builtin_amdgcn_s_setprio(1);
#pragma unroll
        for (int dk = 0; dk < 8; dk += 2) {
            int o0 = r31 * 256 + (dk * 16 + hi * 8) * 2;
            o0 ^= (r31 & 7) << 4;
            const bf8 kf0 = *(const bf8*)(kB + o0);
            s0 = __builtin_amdgcn_mfma_f32_32x32x16_bf16(kf0, qf[dk], s0, 0, 0, 0);
            int o1 = r31 * 256 + ((dk + 1) * 16 + hi * 8) * 2;
            o1 ^= (r31 & 7) << 4;
            const bf8 kf1 = *(const bf8*)(kB + o1);
            s1 = __builtin_amdgcn_mfma_f32_32x32x16_bf16(kf1, qf[dk + 1], s1, 0, 0, 0);
        }
        __builtin_amdgcn_s_setprio(0);

        // ---- V tr-reads; latency hides under softmax (VALU) ----
        asm volatile("" ::: "memory");
        const unsigned vA = smBase + 32768u + (unsigned)((((g << 1) | buf)) << 13) + vLaneOff;
        i32x2 vt_[2][4][2];
#pragma unroll
        for (int ks = 0; ks < 2; ++ks) {
            const unsigned vk = vA + (unsigned)(ks << 12);
#pragma unroll
            for (int dt = 0; dt < 4; ++dt) {
                vt_[ks][dt][0] = tr_read(vk + dt * 512);
                vt_[ks][dt][1] = tr_read(vk + dt * 512 + 2048);
            }
        }

        float p[16];
#pragma unroll
        for (int e = 0; e < 16; ++e) p[e] = s0[e] + s1[e];

        // ---- in-register online softmax (lane-local q), defer-max THR=8 ----
        float mx = p[0];
#pragma unroll
        for (int e = 1; e < 16; ++e) mx = fmaxf(mx, p[e]);
        mx = xmax32(mx) + bias;
        const int need = (mx > m_run + 8.f) ? 1 : 0;
        if (__any(need)) {
            const float mnew = fmaxf(m_run, mx);
            const float corr = __expf(m_run - mnew);
            m_run = mnew;
            l_run *= corr;
#pragma unroll
            for (int dt = 0; dt < 4; ++dt)
#pragma unroll
                for (int e = 0; e < 16; ++e) oa[dt][e] *= corr;
        }
        const float zb = bias - m_run;
        float rs = 0.f;
#pragma unroll
        for (int e = 0; e < 16; ++e) { p[e] = __expf(p[e] + zb); rs += p[e]; }
        l_run += xsum32(rs);

        // ---- pack P -> B-operand fragments (cvt_pk + permlane) ----
        unsigned a0 = cvtpk(p[0], p[1]),  b0 = cvtpk(p[4], p[5]);
        unsigned a1 = cvtpk(p[2], p[3]),  b1 = cvtpk(p[6], p[7]);
        swap32(a0, b0); swap32(a1, b1);
        const bf8 pf0 = mk_bf8w(a0, a1, b0, b1);
        unsigned a2 = cvtpk(p[8], p[9]),   b2 = cvtpk(p[12], p[13]);
        unsigned a3 = cvtpk(p[10], p[11]), b3 = cvtpk(p[14], p[15]);
        swap32(a2, b2); swap32(a3, b3);
        const bf8 pf1 = mk_bf8w(a2, a3, b2, b3);

        // ---- PV swapped: single 8-MFMA cluster ----
        asm volatile("s_waitcnt lgkmcnt(0)");
        __builtin_amdgcn_sched_barrier(0);
        __builtin_amdgcn_s_setprio(1);
#pragma unroll
        for (int ks = 0; ks < 2; ++ks) {
            const bf8 pf = ks ? pf1 : pf0;
#pragma unroll
            for (int dt = 0; dt < 4; ++dt) {
                const bf8 vf = mk_bf8(vt_[ks][dt][0], vt_[ks][dt][1]);
                oa[dt] = __builtin_amdgcn_mfma_f32_32x32x16_bf16(vf, pf, oa[dt], 0, 0, 0);
            }
        }
        __builtin_amdgcn_s_setprio(0);

        // ---- write-late: next tile's staged regs -> LDS ----
        if (t + 1 < NTG) stage_write(buf ^ 1);
    }

    // ---- split-KV merge: group B publishes (O, m, l) via LDS; A combines ----
    __syncthreads();                      // all compute done; K/V LDS reusable
    float* xfer = (float*)(SM + w4 * 16384);   // [64 elems][64 lanes] f32
    float* ml   = (float*)(SM + 65536);        // [4][32][2]
    if (g == 1) {
#pragma unroll
        for (int dt = 0; dt < 4; ++dt)
#pragma unroll
            for (int e = 0; e < 16; ++e)
                xfer[(dt * 16 + e) * 64 + l] = oa[dt][e];
        if (hi == 0) {
            ml[(w4 * 32 + r31) * 2]     = m_run;
            ml[(w4 * 32 + r31) * 2 + 1] = l_run;
        }
    }
    __syncthreads();
    if (g == 0) {
        const float mb = ml[(w4 * 32 + r31) * 2];
        const float lb = ml[(w4 * 32 + r31) * 2 + 1];
        const float m  = fmaxf(m_run, mb);
        const float ca = __expf(m_run - m);
        const float cb = __expf(mb - m);
        const float inv = 1.0f / (l_run * ca + lb * cb);
        float* op = OUT + ((size_t)(bb * ST + qrow)) * (NH * DH) + hh * DH;
#pragma unroll
        for (int dt = 0; dt < 4; ++dt)
#pragma unroll
            for (int rr = 0; rr < 4; ++rr) {
                f32x4 st;
#pragma unroll
                for (int j = 0; j < 4; ++j) {
                    const float ob = xfer[(dt * 16 + rr * 4 + j) * 64 + l];
                    st[j] = (oa[dt][rr * 4 + j] * ca + ob * cb) * inv;
                }
                *(f32x4*)(op + dt * 32 + rr * 8 + hi * 4) = st;
            }
    }
}

extern "C" void kernel_launch(void* const* d_in, const int* in_sizes, int n_in,
                              void* d_out, int out_size, void* d_ws, size_t ws_size,
                              hipStream_t stream) {
    const float* q  = (const float*)d_in[0];
    const float* tk = (const float*)d_in[1];
    const float* tv = (const float*)d_in[2];
    const float* ck = (const float*)d_in[3];
    const float* cv = (const float*)d_in[4];
    const float* bp = (const float*)d_in[5];
    float* out = (float*)d_out;
    attn_fwd<<<dim3((ST / 128) * B_ * NH), 512, 0, stream>>>(q, tk, tv, ck, cv, bp, out);
}

// Round 12
// 148.941 us; speedup vs baseline: 1.1277x; 1.1277x over previous
//
#include <hip/hip_runtime.h>
#include <hip/hip_bf16.h>

typedef __attribute__((ext_vector_type(4))) float f32x4;
typedef __attribute__((ext_vector_type(16))) float f32x16;
typedef __attribute__((ext_vector_type(8))) short bf8;
typedef __attribute__((ext_vector_type(2))) int i32x2;

#define B_ 2
#define ST 2048
#define SC 1024
#define SK 3072
#define NH 16
#define DH 128
#define KVB 32
#define NT 96
#define TGT 64
#define SCALE 0.088388347648318447f
#define LOG2E 1.4426950408889634f

__device__ __forceinline__ i32x2 tr_read(unsigned a) {
    i32x2 d;
    asm volatile("ds_read_b64_tr_b16 %0, %1" : "=v"(d) : "v"(a));
    return d;
}

__device__ __forceinline__ unsigned cvtpk(float lo, float hi) {
    unsigned r;
    asm("v_cvt_pk_bf16_f32 %0, %1, %2" : "=v"(r) : "v"(lo), "v"(hi));
    return r;
}

// v_permlane32_swap_b32: SAFE only with two independently-computed values
// (P-pack, proven R7). BROKEN as copy-then-swap self-reduce (R6/R8).
__device__ __forceinline__ void swap32(unsigned &a, unsigned &b) {
    asm volatile("v_permlane32_swap_b32 %0, %1" : "+v"(a), "+v"(b));
}
__device__ __forceinline__ float xmax32(float x) {
    return fmaxf(x, __shfl_xor(x, 32));
}
__device__ __forceinline__ float xsum32(float x) {
    return x + __shfl_xor(x, 32);
}

__device__ __forceinline__ bf8 mk_bf8(i32x2 a, i32x2 b) {
    union { i32x2 h[2]; bf8 v; } u;
    u.h[0] = a; u.h[1] = b;
    return u.v;
}
__device__ __forceinline__ bf8 mk_bf8w(unsigned w0, unsigned w1, unsigned w2, unsigned w3) {
    union { unsigned w[4]; bf8 v; } u;
    u.w[0] = w0; u.w[1] = w1; u.w[2] = w2; u.w[3] = w3;
    return u.v;
}
// pack 8 fp32 -> 8 bf16 via v_cvt_pk_bf16_f32 (1 op / 2 elems; RNE)
__device__ __forceinline__ bf8 pack_bf8(f32x4 a, f32x4 b) {
    return mk_bf8w(cvtpk(a[0], a[1]), cvtpk(a[2], a[3]),
                   cvtpk(b[0], b[1]), cvtpk(b[2], b[3]));
}

__global__ __launch_bounds__(256, 2)
void attn_fwd(const float* __restrict__ Q,
              const float* __restrict__ TK,
              const float* __restrict__ TV,
              const float* __restrict__ CK,
              const float* __restrict__ CV,
              const float* __restrict__ BP,
              float* __restrict__ OUT)
{
    // R9 structure: 4 waves x 32 q-rows = 128 q-rows/block, swapped QK^T/PV
    // (q = lane&31), in-register log2-domain online softmax.
    // K: XOR-swizzle folded into global source col; LINEAR ds_write.
    // V: tr_read tile permutation folded into global source addr; LINEAR write.
    __shared__ __align__(16) unsigned short Ks[2][KVB * DH];   // 2 x 8 KB
    __shared__ __align__(16) unsigned short Vs[2][KVB * DH];   // 2 x 8 KB

    const int tid = threadIdx.x;
    const int w   = tid >> 6;
    const int l   = tid & 63;
    const int r31 = l & 31;
    const int hi  = l >> 5;

    // XCD-aware mapping: 512 blocks = 8 XCD x 4 bh x 16 q-tiles
    const int bid = blockIdx.x;
    const int xcd = bid & 7;
    const int sub = bid >> 3;
    const int bh  = xcd * 4 + (sub >> 4);
    const int qt  = sub & 15;
    const int bb  = bh >> 4;
    const int hh  = bh & 15;

    const float biasl = BP[0] * LOG2E;          // log2-domain bias

    // ---- Q fragments (B-operand), pre-scaled by SCALE*log2(e) ----
    const int qrow = qt * 128 + w * 32 + r31;
    const float* qp = Q + (((size_t)bb * ST + qrow) * NH + hh) * DH;
    const float qsc = SCALE * LOG2E;
    bf8 qf[8];
#pragma unroll
    for (int dk = 0; dk < 8; ++dk) {
        const f32x4 x0 = *(const f32x4*)(qp + dk * 16 + hi * 8);
        const f32x4 x1 = *(const f32x4*)(qp + dk * 16 + hi * 8 + 4);
        qf[dk] = mk_bf8w(cvtpk(x0[0]*qsc, x0[1]*qsc), cvtpk(x0[2]*qsc, x0[3]*qsc),
                         cvtpk(x1[0]*qsc, x1[1]*qsc), cvtpk(x1[2]*qsc, x1[3]*qsc));
    }

    f32x16 oa[4];
#pragma unroll
    for (int dt = 0; dt < 4; ++dt)
#pragma unroll
        for (int e = 0; e < 16; ++e) oa[dt][e] = 0.f;
    float m_run = -1e30f, l_run = 0.f;

    // staging registers (issue-early / write-late)
    f32x4 skr[2][2], svr[2][2];

    auto stage_load = [&](int t) {
        const int kv0 = t * KVB;
        const float *kb, *vb;
        if (kv0 < ST) {
            const size_t off = (((size_t)bb * ST + kv0) * NH + hh) * DH;
            kb = TK + off; vb = TV + off;
        } else {
            const size_t off = (((size_t)bb * SC + (kv0 - ST)) * NH + hh) * DH;
            kb = CK + off; vb = CV + off;
        }
#pragma unroll
        for (int i = 0; i < 2; ++i) {
            const int c = tid + (i << 8);          // 0..511 16B chunks
            const int krow = c >> 4;               // 0..31
            const int kcol = ((c & 15) ^ (krow & 7)) << 3;
            const float* kp = kb + (size_t)krow * (NH * DH) + kcol;
            skr[i][0] = *(const f32x4*)kp;
            skr[i][1] = *(const f32x4*)(kp + 4);
            const int vkv = (((c >> 8) & 1) << 4) | (((c >> 4) & 1) << 3)
                          | (((c >> 7) & 1) << 2) | ((c >> 1) & 3);
            const int vd  = (((c >> 5) & 3) << 5) | (((c >> 3) & 1) << 4)
                          | ((c & 1) << 3);
            const float* vp = vb + (size_t)vkv * (NH * DH) + vd;
            svr[i][0] = *(const f32x4*)vp;
            svr[i][1] = *(const f32x4*)(vp + 4);
        }
    };

    auto stage_write = [&](int buf) {
#pragma unroll
        for (int i = 0; i < 2; ++i) {
            const int c = tid + (i << 8);
            *(bf8*)((char*)Ks[buf] + c * 16) = pack_bf8(skr[i][0], skr[i][1]);
            *(bf8*)((char*)Vs[buf] + c * 16) = pack_bf8(svr[i][0], svr[i][1]);
        }
    };

    stage_load(0);
    stage_write(0);

    const unsigned vLane = (unsigned)(size_t)&Vs[0][0]
                         + (unsigned)((l >> 4) * 128 + (l & 15) * 8);

    for (int t = 0; t < NT; ++t) {
        __syncthreads();
        if (t + 1 < NT) stage_load(t + 1);
        const int buf = t & 1;
        const float bias = (t >= TGT) ? biasl : 0.f;

        // ---- QK^T swapped: two interleaved accumulators ----
        f32x16 s0, s1;
#pragma unroll
        for (int e = 0; e < 16; ++e) { s0[e] = 0.f; s1[e] = 0.f; }
        __builtin_amdgcn_s_setprio(1);
#pragma unroll
        for (int dk = 0; dk < 8; dk += 2) {
            int o0 = r31 * 256 + (dk * 16 + hi * 8) * 2;
            o0 ^= (r31 & 7) << 4;
            const bf8 kf0 = *(const bf8*)((const char*)Ks[buf] + o0);
            s0 = __builtin_amdgcn_mfma_f32_32x32x16_bf16(kf0, qf[dk], s0, 0, 0, 0);
            int o1 = r31 * 256 + ((dk + 1) * 16 + hi * 8) * 2;
            o1 ^= (r31 & 7) << 4;
            const bf8 kf1 = *(const bf8*)((const char*)Ks[buf] + o1);
            s1 = __builtin_amdgcn_mfma_f32_32x32x16_bf16(kf1, qf[dk + 1], s1, 0, 0, 0);
        }
        __builtin_amdgcn_s_setprio(0);

        // ---- V tr-reads; latency hides under softmax (VALU) ----
        asm volatile("" ::: "memory");
        const unsigned vA = vLane + (unsigned)(buf << 13);
        i32x2 vt_[2][4][2];
#pragma unroll
        for (int ks = 0; ks < 2; ++ks) {
            const unsigned vk = vA + (unsigned)(ks << 12);
#pragma unroll
            for (int dt = 0; dt < 4; ++dt) {
                vt_[ks][dt][0] = tr_read(vk + dt * 512);
                vt_[ks][dt][1] = tr_read(vk + dt * 512 + 2048);
            }
        }

        float p[16];
#pragma unroll
        for (int e = 0; e < 16; ++e) p[e] = s0[e] + s1[e];

        // ---- in-register online softmax, log2 domain, defer-max 8 nats ----
        float mx = p[0];
#pragma unroll
        for (int e = 1; e < 16; ++e) mx = fmaxf(mx, p[e]);
        mx = xmax32(mx) + bias;
        const int need = (mx > m_run + 11.54f) ? 1 : 0;
        if (__any(need)) {
            const float mnew = fmaxf(m_run, mx);
            const float corr = __builtin_amdgcn_exp2f(m_run - mnew);
            m_run = mnew;
            l_run *= corr;
#pragma unroll
            for (int dt = 0; dt < 4; ++dt)
#pragma unroll
                for (int e = 0; e < 16; ++e) oa[dt][e] *= corr;
        }
        const float zb = bias - m_run;
        float rs = 0.f;
#pragma unroll
        for (int e = 0; e < 16; ++e) {
            p[e] = __builtin_amdgcn_exp2f(p[e] + zb);
            rs += p[e];
        }
        l_run += xsum32(rs);

        // ---- pack P -> B-operand fragments (cvt_pk + permlane) ----
        unsigned a0 = cvtpk(p[0], p[1]),  b0 = cvtpk(p[4], p[5]);
        unsigned a1 = cvtpk(p[2], p[3]),  b1 = cvtpk(p[6], p[7]);
        swap32(a0, b0); swap32(a1, b1);
        const bf8 pf0 = mk_bf8w(a0, a1, b0, b1);
        unsigned a2 = cvtpk(p[8], p[9]),   b2 = cvtpk(p[12], p[13]);
        unsigned a3 = cvtpk(p[10], p[11]), b3 = cvtpk(p[14], p[15]);
        swap32(a2, b2); swap32(a3, b3);
        const bf8 pf1 = mk_bf8w(a2, a3, b2, b3);

        // ---- PV swapped: single 8-MFMA cluster ----
        asm volatile("s_waitcnt lgkmcnt(0)");
        __builtin_amdgcn_sched_barrier(0);
        __builtin_amdgcn_s_setprio(1);
#pragma unroll
        for (int ks = 0; ks < 2; ++ks) {
            const bf8 pf = ks ? pf1 : pf0;
#pragma unroll
            for (int dt = 0; dt < 4; ++dt) {
                const bf8 vf = mk_bf8(vt_[ks][dt][0], vt_[ks][dt][1]);
                oa[dt] = __builtin_amdgcn_mfma_f32_32x32x16_bf16(vf, pf, oa[dt], 0, 0, 0);
            }
        }
        __builtin_amdgcn_s_setprio(0);

        // ---- write-late: next tile's staged regs -> LDS ----
        if (t + 1 < NT) stage_write(buf ^ 1);
    }

    // ---- epilogue: normalize, store fp32; lane owns q=r31 ----
    const float inv = 1.0f / l_run;
    float* op = OUT + ((size_t)(bb * ST + qrow)) * (NH * DH) + hh * DH;
#pragma unroll
    for (int dt = 0; dt < 4; ++dt)
#pragma unroll
        for (int rr = 0; rr < 4; ++rr) {
            f32x4 st;
            st[0] = oa[dt][rr * 4 + 0] * inv;
            st[1] = oa[dt][rr * 4 + 1] * inv;
            st[2] = oa[dt][rr * 4 + 2] * inv;
            st[3] = oa[dt][rr * 4 + 3] * inv;
            *(f32x4*)(op + dt * 32 + rr * 8 + hi * 4) = st;
        }
}

extern "C" void kernel_launch(void* const* d_in, const int* in_sizes, int n_in,
                              void* d_out, int out_size, void* d_ws, size_t ws_size,
                              hipStream_t stream) {
    const float* q  = (const float*)d_in[0];
    const float* tk = (const float*)d_in[1];
    const float* tv = (const float*)d_in[2];
    const float* ck = (const float*)d_in[3];
    const float* cv = (const float*)d_in[4];
    const float* bp = (const float*)d_in[5];
    float* out = (float*)d_out;
    attn_fwd<<<dim3((ST / 128) * B_ * NH), 256, 0, stream>>>(q, tk, tv, ck, cv, bp, out);
}